// Round 1
// baseline (206.428 us; speedup 1.0000x reference)
//
#include <hip/hip_runtime.h>
#include <hip/hip_bf16.h>

#define N_ 2048
#define D_ 128
#define B_ 8
#define BM 128
#define BK 64
#define VROWS 144      // 130 useful cols (128 emb + hsq + 1) padded to 144
#define JSPLIT 4
#define JCHUNK (N_ / JSPLIT)   // 512

typedef __attribute__((ext_vector_type(8))) short short8;
typedef __attribute__((ext_vector_type(4))) float f32x4;
typedef __attribute__((ext_vector_type(4))) unsigned short ushort4v;

__device__ __forceinline__ unsigned short f2bf(float x) {
  unsigned int u = __builtin_bit_cast(unsigned int, x);
  u += 0x7fffu + ((u >> 16) & 1u);   // RNE; inputs are finite, no NaN handling needed
  return (unsigned short)(u >> 16);
}

__device__ __forceinline__ void async_lds16(const void* g, void* l) {
  __builtin_amdgcn_global_load_lds(
      (const __attribute__((address_space(1))) void*)g,
      (__attribute__((address_space(3))) void*)l, 16, 0, 0);
}

// Build VT[b][144][2048] bf16 (row d: d<128 -> emb[:,d]; 128 -> hsq; 129 -> 1; >=130 -> 0)
// and hsq[b][2048] fp32. One block per 64 nodes.
__global__ __launch_bounds__(256) void prep_kernel(
    const float* __restrict__ emb, unsigned short* __restrict__ vt,
    float* __restrict__ hsq) {
  __shared__ float semb[64 * 132];   // stride 132 keeps float4 stores 16B-aligned
  __shared__ float shsq[64];
  const int t = threadIdx.x;
  const int bb = blockIdx.x >> 5;
  const int j0 = (blockIdx.x & 31) << 6;
  const float* ebase = emb + ((size_t)(bb * N_ + j0)) * D_;
#pragma unroll
  for (int it = 0; it < 8; ++it) {
    int fidx = it * 1024 + t * 4;
    int j = fidx >> 7, d = fidx & 127;
    const float4 v = *(const float4*)(ebase + (size_t)j * D_ + d);
    *(float4*)&semb[j * 132 + d] = v;
  }
  __syncthreads();
  {
    int j = t >> 2, q = t & 3;
    const float* row = &semb[j * 132 + q * 32];
    float p = 0.f;
#pragma unroll
    for (int x = 0; x < 32; ++x) p += row[x] * row[x];
    p += __shfl_down(p, 2);
    p += __shfl_down(p, 1);
    if (q == 0) { shsq[j] = p; hsq[bb * N_ + j0 + j] = p; }
  }
  __syncthreads();
  unsigned short* vbase = vt + (size_t)bb * VROWS * N_ + j0;
#pragma unroll
  for (int it = 0; it < 36; ++it) {
    int idx = it * 256 + t;
    int d = idx >> 6, j = idx & 63;
    float val;
    if (d < 128)      val = semb[j * 132 + d];
    else if (d == 128) val = shsq[j];
    else if (d == 129) val = 1.0f;
    else               val = 0.0f;
    vbase[(size_t)d * N_ + j] = f2bf(val);
  }
}

// Main: per block, partial M = A[i0:i0+128, j0:j0+512] @ V -> dot with U on the fly.
__global__ __launch_bounds__(256, 2) void gemm_kernel(
    const float* __restrict__ adj, const float* __restrict__ emb,
    const float* __restrict__ hsq, const unsigned short* __restrict__ vt,
    float* __restrict__ partials) {
  __shared__ unsigned short lA[BM * 72];      // [row][64] padded to 72 (144B stride)
  __shared__ unsigned short lV[VROWS * 64];   // [d][64], 16B units XOR-swizzled by (d&7)
  __shared__ float red[4];

  const int t = threadIdx.x;
  const int lane = t & 63, wave = t >> 6;
  const int lhalf = lane & 15, quad = lane >> 4;
  const int bid = blockIdx.x;
  const int b = bid >> 6;
  const int rem = bid & 63;
  const int i0 = (rem >> 2) << 7;             // 16 i-tiles of 128
  const int j0 = (rem & 3) * JCHUNK;          // 4 j-chunks of 512

  const float* abase = adj + ((size_t)b << 22);
  const unsigned short* vtbase = vt + (size_t)b * VROWS * N_;

  f32x4 acc[2][9] = {};

  for (int ki = 0; ki < JCHUNK / BK; ++ki) {
    const int jk = j0 + ki * BK;
    // --- VT tile: 144 rows x 64 cols bf16 = 1152 16B units, async direct-to-LDS.
    // LDS dest is wave-uniform base + lane*16; the XOR swizzle is realized by
    // permuting the per-lane GLOBAL source addresses.
#pragma unroll
    for (int it = 0; it < 4; ++it) {
      int flat = it * 256 + wave * 64 + lane;
      int r = flat >> 3, up = flat & 7;
      int ul = up ^ (r & 7);
      async_lds16(vtbase + (size_t)r * N_ + jk + ul * 8,
                  (char*)lV + (size_t)(it * 256 + wave * 64) * 16);
    }
    if (wave < 2) {
      int flat = 1024 + wave * 64 + lane;
      int r = flat >> 3, up = flat & 7;
      int ul = up ^ (r & 7);
      async_lds16(vtbase + (size_t)r * N_ + jk + ul * 8,
                  (char*)lV + (size_t)(1024 + wave * 64) * 16);
    }
    // --- A tile: 128x64 fp32 -> bf16 -> LDS (padded stride 72)
#pragma unroll
    for (int it = 0; it < 8; ++it) {
      int fidx = it * 1024 + t * 4;
      int row = fidx >> 6, col = fidx & 63;
      const float4 v = *(const float4*)(abase + (size_t)(i0 + row) * N_ + jk + col);
      ushort4v p;
      p.x = f2bf(v.x); p.y = f2bf(v.y); p.z = f2bf(v.z); p.w = f2bf(v.w);
      *(ushort4v*)&lA[row * 72 + col] = p;
    }
    __syncthreads();
    // --- MFMA: wave covers 32 rows (2 m-tiles) x 144 cols (9 n-tiles)
#pragma unroll
    for (int ks = 0; ks < 2; ++ks) {
      const int krow = ks * 32 + quad * 8;
      short8 a0 = *(const short8*)&lA[(wave * 32 + lhalf) * 72 + krow];
      short8 a1 = *(const short8*)&lA[(wave * 32 + 16 + lhalf) * 72 + krow];
#pragma unroll
      for (int nt = 0; nt < 9; ++nt) {
        int r = nt * 16 + lhalf;
        int up = (ks * 4 + quad) ^ (r & 7);
        short8 bfrag = *(const short8*)&lV[r * 64 + up * 8];
        acc[0][nt] = __builtin_amdgcn_mfma_f32_16x16x32_bf16(a0, bfrag, acc[0][nt], 0, 0, 0);
        acc[1][nt] = __builtin_amdgcn_mfma_f32_16x16x32_bf16(a1, bfrag, acc[1][nt], 0, 0, 0);
      }
    }
    __syncthreads();
  }

  // --- epilogue: part += acc[i][d] * U[i][d], U from emb/hsq on the fly.
  // C/D layout: col = lane&15, row = quad*4 + reg.
  float part = 0.f;
  const float* erow_base = emb + (size_t)b * N_ * D_;
#pragma unroll
  for (int mt = 0; mt < 2; ++mt) {
#pragma unroll
    for (int r = 0; r < 4; ++r) {
      int i = i0 + wave * 32 + mt * 16 + quad * 4 + r;
      const float* erow = erow_base + (size_t)i * D_;
#pragma unroll
      for (int nt = 0; nt < 8; ++nt) {
        int d = nt * 16 + lhalf;
        part += acc[mt][nt][r] * (-2.0f * erow[d]);
      }
      float u8 = (lhalf == 0) ? 1.0f : (lhalf == 1) ? hsq[b * N_ + i] : 0.0f;
      part += acc[mt][8][r] * u8;
    }
  }
#pragma unroll
  for (int off = 32; off > 0; off >>= 1) part += __shfl_down(part, off);
  if (lane == 0) red[wave] = part;
  __syncthreads();
  if (t == 0) partials[bid] = red[0] + red[1] + red[2] + red[3];
}

__global__ void finish_kernel(const float* __restrict__ partials,
                              float* __restrict__ out) {
  double s = 0.0;
  int t = threadIdx.x;
  for (int i = t; i < B_ * 16 * JSPLIT; i += 64) s += (double)partials[i];
#pragma unroll
  for (int off = 32; off > 0; off >>= 1) s += __shfl_down(s, off);
  if (t == 0) out[0] = (float)(s / (double)((size_t)B_ * N_));
}

extern "C" void kernel_launch(void* const* d_in, const int* in_sizes, int n_in,
                              void* d_out, int out_size, void* d_ws, size_t ws_size,
                              hipStream_t stream) {
  const float* adj = (const float*)d_in[0];
  const float* emb = (const float*)d_in[1];
  // ws layout: hsq (64 KiB) | VT bf16 (4.5 MiB) | partials (2 KiB)
  float* hsq = (float*)d_ws;
  unsigned short* vt = (unsigned short*)((char*)d_ws + 65536);
  float* partials = (float*)((char*)d_ws + 65536 + (size_t)B_ * VROWS * N_ * 2);

  prep_kernel<<<B_ * (N_ / 64), 256, 0, stream>>>(emb, vt, hsq);
  gemm_kernel<<<B_ * 16 * JSPLIT, 256, 0, stream>>>(adj, emb, hsq, vt, partials);
  finish_kernel<<<1, 64, 0, stream>>>(partials, (float*)d_out);
}